// Round 8
// baseline (135.166 us; speedup 1.0000x reference)
//
#include <hip/hip_runtime.h>
#include <hip/hip_bf16.h>

typedef unsigned int uint32;
typedef unsigned short u16;

#define NPT 128        // grid nodes per dim
#define RNK 16         // TT rank
#define MIDROW 264     // bf16 elems per LDS row for mid cores (256 + 8 pad) = 528 B
#define MIDROW_U32 132
// LDS: the two mid cores only (edges read straight from L1-resident global)
#define SMEM_BYTES (2*NPT*MIDROW*2)   // 135168 B -> 1 block/CU

#if defined(__has_builtin)
#if __has_builtin(__builtin_amdgcn_fdot2_f32_bf16)
#define HAVE_BFDOT2 1
#endif
#endif

__device__ __forceinline__ float bl(uint32 u){ return __uint_as_float(u << 16); }
__device__ __forceinline__ float bh(uint32 u){ return __uint_as_float(u & 0xffff0000u); }

__device__ __forceinline__ uint32 pk2(float a, float b){
  __hip_bfloat16 l = __float2bfloat16(a);
  __hip_bfloat16 h = __float2bfloat16(b);
  return (uint32)(*(u16*)&l) | ((uint32)(*(u16*)&h) << 16);
}

#ifdef HAVE_BFDOT2
typedef __bf16 v2bf __attribute__((ext_vector_type(2)));
__device__ __forceinline__ v2bf bc(uint32 u){ return __builtin_bit_cast(v2bf, u); }

// dot of packed-bf16 v (8 u32) with 16 bf16 core elems in two uint4
__device__ __forceinline__ float dot16b(const uint32* vp, uint4 U0, uint4 U1) {
  float s0 = 0.f, s1 = 0.f;
  s0 = __builtin_amdgcn_fdot2_f32_bf16(bc(vp[0]), bc(U0.x), s0, false);
  s0 = __builtin_amdgcn_fdot2_f32_bf16(bc(vp[1]), bc(U0.y), s0, false);
  s0 = __builtin_amdgcn_fdot2_f32_bf16(bc(vp[2]), bc(U0.z), s0, false);
  s0 = __builtin_amdgcn_fdot2_f32_bf16(bc(vp[3]), bc(U0.w), s0, false);
  s1 = __builtin_amdgcn_fdot2_f32_bf16(bc(vp[4]), bc(U1.x), s1, false);
  s1 = __builtin_amdgcn_fdot2_f32_bf16(bc(vp[5]), bc(U1.y), s1, false);
  s1 = __builtin_amdgcn_fdot2_f32_bf16(bc(vp[6]), bc(U1.z), s1, false);
  s1 = __builtin_amdgcn_fdot2_f32_bf16(bc(vp[7]), bc(U1.w), s1, false);
  return s0 + s1;
}
#else
__device__ __forceinline__ float dot16(const float* v, uint4 U0, uint4 U1) {
  float s0 = fmaf(v[1],  bh(U0.x), v[0]*bl(U0.x));
  s0 = fmaf(v[2],  bl(U0.y), s0); s0 = fmaf(v[3],  bh(U0.y), s0);
  float s1 = fmaf(v[5],  bh(U0.z), v[4]*bl(U0.z));
  s1 = fmaf(v[6],  bl(U0.w), s1); s1 = fmaf(v[7],  bh(U0.w), s1);
  float s2 = fmaf(v[9],  bh(U1.x), v[8]*bl(U1.x));
  s2 = fmaf(v[10], bl(U1.y), s2); s2 = fmaf(v[11], bh(U1.y), s2);
  float s3 = fmaf(v[13], bh(U1.z), v[12]*bl(U1.z));
  s3 = fmaf(v[14], bl(U1.w), s3); s3 = fmaf(v[15], bh(U1.w), s3);
  return (s0 + s1) + (s2 + s3);
}
#endif

// clamped remap: returns xc in [0, 127]
__device__ __forceinline__ float remap_clamp(float x) {
  float xr = (x + 1.0f) * 0.5f * (float)(NPT - 1);
  return fminf(fmaxf(xr, 0.0f), (float)(NPT - 1));
}

// one middle-dim contraction: v <- v @ ((1-w)*Lo + w*Hi), rows in LDS as [n][j*16+i] bf16.
// n0 = min(floor(xc), 126): rows always adjacent (lerp(c126,c127,1) == c127).
// b128 gather conflicts (~4M cyc) are structural: 16B-aligned starts -> 8 four-bank
// classes, multinomial over random n0; swizzles measured no-op (round 4).
__device__ __forceinline__ void tt_mid(const uint32* __restrict__ base, float xc, float v[16]) {
  int n0 = min((int)xc, NPT - 2);
  float w = xc - (float)n0;
  const uint32* r0 = base + n0 * MIDROW_U32;
  const uint32* r1 = r0 + MIDROW_U32;

#ifdef HAVE_BFDOT2
  uint32 vp[8];
#pragma unroll
  for (int k = 0; k < 8; ++k) vp[k] = pk2(v[2*k], v[2*k+1]);
#endif

  float nv[16];
#pragma unroll
  for (int j = 0; j < 16; ++j) {
    const uint4* p0 = (const uint4*)(r0 + j * 8);
    const uint4* p1 = (const uint4*)(r1 + j * 8);
    uint4 A0 = p0[0], A1 = p0[1];
    uint4 B0 = p1[0], B1 = p1[1];
#ifdef HAVE_BFDOT2
    float a = dot16b(vp, A0, A1);
    float b = dot16b(vp, B0, B1);
#else
    float a = dot16(v, A0, A1);
    float b = dot16(v, B0, B1);
#endif
    nv[j] = fmaf(w, b - a, a);
  }
#pragma unroll
  for (int j = 0; j < 16; ++j) v[j] = nv[j];
}

// Staging chunk t in [0,1024): n=t>>3, jq=(t>>1)&3 (j-quad), h=t&1 (i-octet).
// Loads: 8x float4 [i=8h+k][n][4jq..4jq+3] (fully coalesced, stride 8 KB in i).
__device__ __forceinline__ void stage_load4(const float* __restrict__ g, int t, float4* f) {
  int n = t >> 3, jq = (t >> 1) & 3, h = t & 1;
  const float* s = g + (h * 8) * 2048 + n * 16 + jq * 4;
#pragma unroll
  for (int k = 0; k < 8; ++k) f[k] = *(const float4*)(s + k * 2048);
}
// Pack + 4x ds_write_b128: fragment (4jq+jj) gets i=8h..8h+7 from lanes of f.
__device__ __forceinline__ void stage_write4(u16* __restrict__ dst, int t, const float4* f) {
  int n = t >> 3, jq = (t >> 1) & 3, h = t & 1;
  u16* row = dst + n * MIDROW + h * 8;
  {
    uint4 w = make_uint4(pk2(f[0].x,f[1].x), pk2(f[2].x,f[3].x),
                         pk2(f[4].x,f[5].x), pk2(f[6].x,f[7].x));
    *(uint4*)(row + (4*jq+0) * 16) = w;
  }
  {
    uint4 w = make_uint4(pk2(f[0].y,f[1].y), pk2(f[2].y,f[3].y),
                         pk2(f[4].y,f[5].y), pk2(f[6].y,f[7].y));
    *(uint4*)(row + (4*jq+1) * 16) = w;
  }
  {
    uint4 w = make_uint4(pk2(f[0].z,f[1].z), pk2(f[2].z,f[3].z),
                         pk2(f[4].z,f[5].z), pk2(f[6].z,f[7].z));
    *(uint4*)(row + (4*jq+2) * 16) = w;
  }
  {
    uint4 w = make_uint4(pk2(f[0].w,f[1].w), pk2(f[2].w,f[3].w),
                         pk2(f[4].w,f[5].w), pk2(f[6].w,f[7].w));
    *(uint4*)(row + (4*jq+3) * 16) = w;
  }
}

// Two-phase schedule, 1024 thr, 1 pt/thread, 1 block/CU (LDS 132 KB):
//   issue g0, stage c1, issue c2 loads (held in 32 VGPRs), dim0, BARRIER,
//   dim1(c1), pack+write c2 (vmcnt retired under dim1), BARRIER, dim2(c2), dim3.
// VMEM issue order (g0 -> c1 -> c2) gives counted vmcnt waits: dim0 waits only g0,
// c1 writes wait only c1; c2's latency is hidden under dim0+barrier+dim1 (~1000 cyc).
// __launch_bounds__(1024,1): 16 waves/CU = 4/SIMD -> VGPR cap 128. Held c2 (32) +
// dim1 working set (~65) fits; rounds 4/5 failed this schedule ONLY because their
// launch_bounds decoded to a 64-reg cap and spilled.
__global__ __launch_bounds__(1024, 1) void tt_kernel(
    const float* __restrict__ x,  const float* __restrict__ g0,
    const float* __restrict__ g1, const float* __restrict__ g2,
    const float* __restrict__ g3, float* __restrict__ out, int npts)
{
  extern __shared__ char smem[];
  u16* c1 = (u16*)smem;                          // [128][264] bf16
  u16* c2 = c1 + NPT * MIDROW;                   // [128][264] bf16

  const int tid = (int)threadIdx.x;
  const int p0i = (int)blockIdx.x * 1024 + tid;
  const int pc  = min(p0i, npts - 1);

  // x + dim-0 row pair issued first (oldest in vmcnt queue)
  float4 xv = reinterpret_cast<const float4*>(x)[pc];
  float xc0 = remap_clamp(xv.x);
  int   d0n = min((int)xc0, NPT - 2);
  float d0w = xc0 - (float)d0n;
  const float4* Lg = (const float4*)(g0 + d0n * 16);   // [0..3]=row n0, [4..7]=row n0+1

  // phase 0: stage c1 (immediate pack+write), then issue c2 loads (held)
  float4 f1[8];
  stage_load4(g1, tid, f1);
  stage_write4(c1, tid, f1);

  float4 f2[8];
  stage_load4(g2, tid, f2);     // retire under dim0 + barrier + dim1

  // dim 0: lerp core0 row-pair from global (L1-hot 8 KB)
  float v[16];
#pragma unroll
  for (int k = 0; k < 4; ++k) {
    float4 l = Lg[k], h = Lg[k + 4];
    v[4*k+0] = fmaf(d0w, h.x - l.x, l.x);
    v[4*k+1] = fmaf(d0w, h.y - l.y, l.y);
    v[4*k+2] = fmaf(d0w, h.z - l.z, l.z);
    v[4*k+3] = fmaf(d0w, h.w - l.w, l.w);
  }

  __syncthreads();                 // c1 visible

  // dim 1 (c1)
  tt_mid((const uint32*)c1, remap_clamp(xv.y), v);

  // pack + write c2 (loads long retired; pack VALU sits in dim-1's shadow region)
  stage_write4(c2, tid, f2);

  __syncthreads();                 // c2 visible

  // dim 2 (c2)
  tt_mid((const uint32*)c2, remap_clamp(xv.z), v);

  // dim 3: lerp core3 column from global (L1-hot 8 KB) and dot
  float acc;
  {
    float xc = remap_clamp(xv.w);
    int n0 = min((int)xc, NPT - 2);
    float w = xc - (float)n0;
    float a0 = 0.f, a1 = 0.f, a2 = 0.f, a3 = 0.f;
#pragma unroll
    for (int i = 0; i < 4; ++i) {
#pragma unroll
      for (int k = 0; k < 4; ++k) {
        const float* col = g3 + (4 * i + k) * NPT + n0;
        float lo = col[0], hi = col[1];
        float cv = fmaf(w, hi - lo, lo);
        if (k == 0) a0 = fmaf(v[4*i+0], cv, a0);
        else if (k == 1) a1 = fmaf(v[4*i+1], cv, a1);
        else if (k == 2) a2 = fmaf(v[4*i+2], cv, a2);
        else a3 = fmaf(v[4*i+3], cv, a3);
      }
    }
    acc = (a0 + a1) + (a2 + a3);
  }
  if (p0i < npts) out[p0i] = acc;
}

extern "C" void kernel_launch(void* const* d_in, const int* in_sizes, int n_in,
                              void* d_out, int out_size, void* d_ws, size_t ws_size,
                              hipStream_t stream) {
  const float* x  = (const float*)d_in[0];
  const float* g0 = (const float*)d_in[1];
  const float* g1 = (const float*)d_in[2];
  const float* g2 = (const float*)d_in[3];
  const float* g3 = (const float*)d_in[4];
  float* out = (float*)d_out;

  int B = in_sizes[0] / 4;
  // >64 KB dynamic LDS needs the opt-in attribute (host-side call, capture-safe)
  hipFuncSetAttribute(reinterpret_cast<const void*>(tt_kernel),
                      hipFuncAttributeMaxDynamicSharedMemorySize, SMEM_BYTES);
  int block = 1024;
  int grid = (B + block - 1) / block;   // 256 blocks -> 1 per CU
  tt_kernel<<<grid, block, SMEM_BYTES, stream>>>(x, g0, g1, g2, g3, out, B);
}

// Round 10
// 124.559 us; speedup vs baseline: 1.0852x; 1.0852x over previous
//
#include <hip/hip_runtime.h>
#include <hip/hip_bf16.h>

typedef unsigned int uint32;
typedef unsigned short u16;

#define NPT 128        // grid nodes per dim
#define RNK 16         // TT rank
#define MIDROW 264     // bf16 elems per LDS row for mid cores (256 + 8 pad) = 528 B
#define MIDROW_U32 132
// LDS: the two mid cores only (edges read straight from L1-resident global)
#define SMEM_BYTES (2*NPT*MIDROW*2)   // 135168 B -> 1 block/CU

#if defined(__has_builtin)
#if __has_builtin(__builtin_amdgcn_fdot2_f32_bf16)
#define HAVE_BFDOT2 1
#endif
#endif

__device__ __forceinline__ float bl(uint32 u){ return __uint_as_float(u << 16); }
__device__ __forceinline__ float bh(uint32 u){ return __uint_as_float(u & 0xffff0000u); }

__device__ __forceinline__ uint32 pk2(float a, float b){
  __hip_bfloat16 l = __float2bfloat16(a);
  __hip_bfloat16 h = __float2bfloat16(b);
  return (uint32)(*(u16*)&l) | ((uint32)(*(u16*)&h) << 16);
}

#ifdef HAVE_BFDOT2
typedef __bf16 v2bf __attribute__((ext_vector_type(2)));
__device__ __forceinline__ v2bf bc(uint32 u){ return __builtin_bit_cast(v2bf, u); }

// dot of packed-bf16 v (8 u32) with 16 bf16 core elems in two uint4
__device__ __forceinline__ float dot16b(const uint32* vp, uint4 U0, uint4 U1) {
  float s0 = 0.f, s1 = 0.f;
  s0 = __builtin_amdgcn_fdot2_f32_bf16(bc(vp[0]), bc(U0.x), s0, false);
  s0 = __builtin_amdgcn_fdot2_f32_bf16(bc(vp[1]), bc(U0.y), s0, false);
  s0 = __builtin_amdgcn_fdot2_f32_bf16(bc(vp[2]), bc(U0.z), s0, false);
  s0 = __builtin_amdgcn_fdot2_f32_bf16(bc(vp[3]), bc(U0.w), s0, false);
  s1 = __builtin_amdgcn_fdot2_f32_bf16(bc(vp[4]), bc(U1.x), s1, false);
  s1 = __builtin_amdgcn_fdot2_f32_bf16(bc(vp[5]), bc(U1.y), s1, false);
  s1 = __builtin_amdgcn_fdot2_f32_bf16(bc(vp[6]), bc(U1.z), s1, false);
  s1 = __builtin_amdgcn_fdot2_f32_bf16(bc(vp[7]), bc(U1.w), s1, false);
  return s0 + s1;
}
#else
__device__ __forceinline__ float dot16(const float* v, uint4 U0, uint4 U1) {
  float s0 = fmaf(v[1],  bh(U0.x), v[0]*bl(U0.x));
  s0 = fmaf(v[2],  bl(U0.y), s0); s0 = fmaf(v[3],  bh(U0.y), s0);
  float s1 = fmaf(v[5],  bh(U0.z), v[4]*bl(U0.z));
  s1 = fmaf(v[6],  bl(U0.w), s1); s1 = fmaf(v[7],  bh(U0.w), s1);
  float s2 = fmaf(v[9],  bh(U1.x), v[8]*bl(U1.x));
  s2 = fmaf(v[10], bl(U1.y), s2); s2 = fmaf(v[11], bh(U1.y), s2);
  float s3 = fmaf(v[13], bh(U1.z), v[12]*bl(U1.z));
  s3 = fmaf(v[14], bl(U1.w), s3); s3 = fmaf(v[15], bh(U1.w), s3);
  return (s0 + s1) + (s2 + s3);
}
#endif

// clamped remap: returns xc in [0, 127]
__device__ __forceinline__ float remap_clamp(float x) {
  float xr = (x + 1.0f) * 0.5f * (float)(NPT - 1);
  return fminf(fmaxf(xr, 0.0f), (float)(NPT - 1));
}

// compute nv[j] for j in [j0, j1): one j-slice of the middle contraction
#ifdef HAVE_BFDOT2
__device__ __forceinline__ void mid_slice(const uint32* r0, const uint32* r1, float w,
                                          const uint32* vp, float* nv, int j0, int j1) {
#pragma unroll
  for (int j = j0; j < j1; ++j) {
    const uint4* p0 = (const uint4*)(r0 + j * 8);
    const uint4* p1 = (const uint4*)(r1 + j * 8);
    uint4 A0 = p0[0], A1 = p0[1], B0 = p1[0], B1 = p1[1];
    float a = dot16b(vp, A0, A1);
    float b = dot16b(vp, B0, B1);
    nv[j] = fmaf(w, b - a, a);
  }
}
#endif

// full middle-dim contraction (used for dim 2): v <- v @ ((1-w)*Lo + w*Hi)
// rows in LDS as [n][j*16+i] bf16. n0 = min(floor(xc),126): rows always adjacent.
// b128 gather conflicts (~4M cyc) are structural (16B-aligned starts -> 8 bank classes);
// swizzles measured no-op (round 4).
__device__ __forceinline__ void tt_mid(const uint32* __restrict__ base, float xc, float v[16]) {
  int n0 = min((int)xc, NPT - 2);
  float w = xc - (float)n0;
  const uint32* r0 = base + n0 * MIDROW_U32;
  const uint32* r1 = r0 + MIDROW_U32;

#ifdef HAVE_BFDOT2
  uint32 vp[8];
#pragma unroll
  for (int k = 0; k < 8; ++k) vp[k] = pk2(v[2*k], v[2*k+1]);
  float nv[16];
  mid_slice(r0, r1, w, vp, nv, 0, 16);
#else
  float nv[16];
#pragma unroll
  for (int j = 0; j < 16; ++j) {
    const uint4* p0 = (const uint4*)(r0 + j * 8);
    const uint4* p1 = (const uint4*)(r1 + j * 8);
    uint4 A0 = p0[0], A1 = p0[1], B0 = p1[0], B1 = p1[1];
    float a = dot16(v, A0, A1);
    float b = dot16(v, B0, B1);
    nv[j] = fmaf(w, b - a, a);
  }
#endif
#pragma unroll
  for (int j = 0; j < 16; ++j) v[j] = nv[j];
}

// Staging chunk t in [0,2048): n=t>>4, q=(t>>1)&7 (j-pair), h=t&1 (i-octet).
// loads: 8x float2 of [i=8h+k][n][j=2q,2q+1]; live state 16 regs (spill-safe under
// the observed 64-reg allocation). writes: 2x ds_write_b128, conflict-light.
__device__ __forceinline__ void stage_loads2(const float* __restrict__ g, int t, float2* f) {
  int n = t >> 4, q = (t >> 1) & 7, h = t & 1;
  const float* s = g + (h * 8) * 2048 + n * 16 + q * 2;
#pragma unroll
  for (int k = 0; k < 8; ++k) f[k] = *(const float2*)(s + k * 2048);
}
__device__ __forceinline__ void stage_write2(u16* __restrict__ dst, int t, const float2* f) {
  int n = t >> 4, q = (t >> 1) & 7, h = t & 1;
  uint4 w0, w1;
  w0.x = pk2(f[0].x, f[1].x); w0.y = pk2(f[2].x, f[3].x);
  w0.z = pk2(f[4].x, f[5].x); w0.w = pk2(f[6].x, f[7].x);
  w1.x = pk2(f[0].y, f[1].y); w1.y = pk2(f[2].y, f[3].y);
  w1.z = pk2(f[4].y, f[5].y); w1.w = pk2(f[6].y, f[7].y);
  *(uint4*)(dst + n * MIDROW + (2 * q) * 16 + h * 8)     = w0;
  *(uint4*)(dst + n * MIDROW + (2 * q + 1) * 16 + h * 8) = w1;
}
__device__ __forceinline__ void stage_chunk(const float* __restrict__ g,
                                            u16* __restrict__ dst, int t) {
  float2 f[8];
  stage_loads2(g, t, f);
  stage_write2(dst, t, f);
}

// Schedule (1024 thr, 1 pt/thread, 1 block/CU, LDS 132 KB):
//   phase 0: stage c1 ONLY (1 MB/CU L2 stream, was 2 MB) + dim 0 from global g0.
//   barrier.
//   phase 1: dim 1 (c1) with c2's staging INTERLEAVED INSIDE the barrier region:
//            issue chunk-A loads -> j=0..7 -> write A, issue B -> j=8..15 -> write B.
//            c2's 1 MB stream + L2 latency hides under dim-1's DS/VALU work; loads are
//            consumed within the same region (no cross-barrier flight -> no vmcnt-drain
//            stall, no spill: rounds 4/5/8 proved holding staged regs across a barrier
//            spills at the 64-reg allocation this kernel always gets).
//   barrier. phase 2: dim 2 (c2), dim 3 from global g3.
__global__ __launch_bounds__(1024, 1) void tt_kernel(
    const float* __restrict__ x,  const float* __restrict__ g0,
    const float* __restrict__ g1, const float* __restrict__ g2,
    const float* __restrict__ g3, float* __restrict__ out, int npts)
{
  extern __shared__ char smem[];
  u16* c1 = (u16*)smem;                          // [128][264] bf16
  u16* c2 = c1 + NPT * MIDROW;                   // [128][264] bf16

  const int tid = (int)threadIdx.x;
  const int p0i = (int)blockIdx.x * 1024 + tid;
  const int pc  = min(p0i, npts - 1);

  // x + dim-0 row pair issued first
  float4 xv = reinterpret_cast<const float4*>(x)[pc];
  float xc0 = remap_clamp(xv.x);
  int   d0n = min((int)xc0, NPT - 2);
  float d0w = xc0 - (float)d0n;
  const float4* Lg = (const float4*)(g0 + d0n * 16);   // [0..3]=row n0, [4..7]=row n0+1

  // phase 0: stage c1 only (immediate pack+write; 16 transient regs)
  stage_chunk(g1, c1, tid);
  stage_chunk(g1, c1, tid + 1024);

  // dim 0: lerp core0 row-pair from global (L1-hot 8 KB)
  float v[16];
#pragma unroll
  for (int k = 0; k < 4; ++k) {
    float4 l = Lg[k], h = Lg[k + 4];
    v[4*k+0] = fmaf(d0w, h.x - l.x, l.x);
    v[4*k+1] = fmaf(d0w, h.y - l.y, l.y);
    v[4*k+2] = fmaf(d0w, h.z - l.z, l.z);
    v[4*k+3] = fmaf(d0w, h.w - l.w, l.w);
  }

  __syncthreads();                 // c1 visible

  // ---- phase 1: dim 1 (c1) with c2 staging interleaved ----
  {
    float xc = remap_clamp(xv.y);
    int n0 = min((int)xc, NPT - 2);
    float w = xc - (float)n0;
    const uint32* r0 = (const uint32*)c1 + n0 * MIDROW_U32;
    const uint32* r1 = r0 + MIDROW_U32;

#ifdef HAVE_BFDOT2
    uint32 vp[8];
#pragma unroll
    for (int k = 0; k < 8; ++k) vp[k] = pk2(v[2*k], v[2*k+1]);   // v dead after pack

    float2 fA[8];
    stage_loads2(g2, tid, fA);           // issue A; retires under j=0..7

    float nv[16];
    mid_slice(r0, r1, w, vp, nv, 0, 8);

    stage_write2(c2, tid, fA);
    float2 fB[8];
    stage_loads2(g2, tid + 1024, fB);    // issue B; retires under j=8..15

    mid_slice(r0, r1, w, vp, nv, 8, 16);

    stage_write2(c2, tid + 1024, fB);

#pragma unroll
    for (int j = 0; j < 16; ++j) v[j] = nv[j];
#else
    // fallback path: stage c2 first, then plain tt_mid
    stage_chunk(g2, c2, tid);
    stage_chunk(g2, c2, tid + 1024);
    tt_mid((const uint32*)c1, xc, v);
#endif
  }

  __syncthreads();                 // c2 visible

  // ---- dim 2 (c2) ----
  tt_mid((const uint32*)c2, remap_clamp(xv.z), v);

  // ---- dim 3: lerp core3 column from global (L1-hot 8 KB) and dot ----
  float acc;
  {
    float xc = remap_clamp(xv.w);
    int n0 = min((int)xc, NPT - 2);
    float w = xc - (float)n0;
    float a0 = 0.f, a1 = 0.f, a2 = 0.f, a3 = 0.f;
#pragma unroll
    for (int i = 0; i < 4; ++i) {
#pragma unroll
      for (int k = 0; k < 4; ++k) {
        const float* col = g3 + (4 * i + k) * NPT + n0;
        float lo = col[0], hi = col[1];
        float cv = fmaf(w, hi - lo, lo);
        if (k == 0) a0 = fmaf(v[4*i+0], cv, a0);
        else if (k == 1) a1 = fmaf(v[4*i+1], cv, a1);
        else if (k == 2) a2 = fmaf(v[4*i+2], cv, a2);
        else a3 = fmaf(v[4*i+3], cv, a3);
      }
    }
    acc = (a0 + a1) + (a2 + a3);
  }
  if (p0i < npts) out[p0i] = acc;
}

extern "C" void kernel_launch(void* const* d_in, const int* in_sizes, int n_in,
                              void* d_out, int out_size, void* d_ws, size_t ws_size,
                              hipStream_t stream) {
  const float* x  = (const float*)d_in[0];
  const float* g0 = (const float*)d_in[1];
  const float* g1 = (const float*)d_in[2];
  const float* g2 = (const float*)d_in[3];
  const float* g3 = (const float*)d_in[4];
  float* out = (float*)d_out;

  int B = in_sizes[0] / 4;
  // >64 KB dynamic LDS needs the opt-in attribute (host-side call, capture-safe)
  hipFuncSetAttribute(reinterpret_cast<const void*>(tt_kernel),
                      hipFuncAttributeMaxDynamicSharedMemorySize, SMEM_BYTES);
  int block = 1024;
  int grid = (B + block - 1) / block;   // 256 blocks -> 1 per CU
  tt_kernel<<<grid, block, SMEM_BYTES, stream>>>(x, g0, g1, g2, g3, out, B);
}

// Round 11
// 79.556 us; speedup vs baseline: 1.6990x; 1.5657x over previous
//
#include <hip/hip_runtime.h>
#include <hip/hip_bf16.h>

typedef unsigned int uint32;
typedef unsigned short u16;

#define NPT 128        // grid nodes per dim
#define RNK 16         // TT rank
#define MIDROW 264     // bf16 elems per LDS row for mid cores (256 + 8 pad) = 528 B
#define MIDROW_U32 132
#define EDGEROW 20     // fp32 elems per LDS row for edge cores (16 + 4 pad) = 80 B
#define SMEM_BYTES (2*NPT*MIDROW*2 + 2*NPT*EDGEROW*4)   // 135168 + 20480 = 155648 B

#if defined(__has_builtin)
#if __has_builtin(__builtin_amdgcn_fdot2_f32_bf16)
#define HAVE_BFDOT2 1
#endif
#endif

__device__ __forceinline__ float bl(uint32 u){ return __uint_as_float(u << 16); }
__device__ __forceinline__ float bh(uint32 u){ return __uint_as_float(u & 0xffff0000u); }

#ifdef HAVE_BFDOT2
typedef __bf16 v2bf __attribute__((ext_vector_type(2)));
__device__ __forceinline__ v2bf bc(uint32 u){ return __builtin_bit_cast(v2bf, u); }

// dot of packed-bf16 v (8 u32) with 16 bf16 core elems in two uint4
__device__ __forceinline__ float dot16b(const uint32* vp, uint4 U0, uint4 U1) {
  float s0 = 0.f, s1 = 0.f;
  s0 = __builtin_amdgcn_fdot2_f32_bf16(bc(vp[0]), bc(U0.x), s0, false);
  s0 = __builtin_amdgcn_fdot2_f32_bf16(bc(vp[1]), bc(U0.y), s0, false);
  s0 = __builtin_amdgcn_fdot2_f32_bf16(bc(vp[2]), bc(U0.z), s0, false);
  s0 = __builtin_amdgcn_fdot2_f32_bf16(bc(vp[3]), bc(U0.w), s0, false);
  s1 = __builtin_amdgcn_fdot2_f32_bf16(bc(vp[4]), bc(U1.x), s1, false);
  s1 = __builtin_amdgcn_fdot2_f32_bf16(bc(vp[5]), bc(U1.y), s1, false);
  s1 = __builtin_amdgcn_fdot2_f32_bf16(bc(vp[6]), bc(U1.z), s1, false);
  s1 = __builtin_amdgcn_fdot2_f32_bf16(bc(vp[7]), bc(U1.w), s1, false);
  return s0 + s1;
}
#else
// fallback: unpack + fmaf
__device__ __forceinline__ float dot16(const float* v, uint4 U0, uint4 U1) {
  float s0 = fmaf(v[1],  bh(U0.x), v[0]*bl(U0.x));
  s0 = fmaf(v[2],  bl(U0.y), s0); s0 = fmaf(v[3],  bh(U0.y), s0);
  float s1 = fmaf(v[5],  bh(U0.z), v[4]*bl(U0.z));
  s1 = fmaf(v[6],  bl(U0.w), s1); s1 = fmaf(v[7],  bh(U0.w), s1);
  float s2 = fmaf(v[9],  bh(U1.x), v[8]*bl(U1.x));
  s2 = fmaf(v[10], bl(U1.y), s2); s2 = fmaf(v[11], bh(U1.y), s2);
  float s3 = fmaf(v[13], bh(U1.z), v[12]*bl(U1.z));
  s3 = fmaf(v[14], bl(U1.w), s3); s3 = fmaf(v[15], bh(U1.w), s3);
  return (s0 + s1) + (s2 + s3);
}
#endif

// one middle-dim contraction: v <- v @ ((1-w)*Lo + w*Hi), core rows in LDS as [n][j*16+i] bf16
// (b128 start banks are 16B-aligned -> only 8 four-bank classes exist; 32 banks / 4 per
//  access = max 8 concurrent b128 reads, so the ~4M conflict cycles are a structural floor
//  for the random-row gather; swizzles measured no-op in round 4.)
__device__ __forceinline__ void tt_mid(const uint32* __restrict__ base, float xc, float v[16]) {
  int n0 = (int)xc;
  float w = xc - (float)n0;
  int n1 = min(n0 + 1, NPT - 1);
  const uint32* r0 = base + n0 * MIDROW_U32;
  const uint32* r1 = base + n1 * MIDROW_U32;

#ifdef HAVE_BFDOT2
  // pack v into bf16 pairs once per dim (amortized over 16 j)
  uint32 vp[8];
#pragma unroll
  for (int k = 0; k < 8; ++k) {
    __hip_bfloat16 l = __float2bfloat16(v[2*k]);
    __hip_bfloat16 h = __float2bfloat16(v[2*k+1]);
    vp[k] = (uint32)(*(u16*)&l) | ((uint32)(*(u16*)&h) << 16);
  }
#endif

  float nv[16];
#pragma unroll
  for (int j = 0; j < 16; ++j) {
    const uint4* p0 = (const uint4*)(r0 + j * 8);
    const uint4* p1 = (const uint4*)(r1 + j * 8);
    uint4 A0 = p0[0], A1 = p0[1];
    uint4 B0 = p1[0], B1 = p1[1];
#ifdef HAVE_BFDOT2
    float a = dot16b(vp, A0, A1);
    float b = dot16b(vp, B0, B1);
#else
    float a = dot16(v, A0, A1);
    float b = dot16(v, B0, B1);
#endif
    nv[j] = fmaf(w, b - a, a);
  }
#pragma unroll
  for (int j = 0; j < 16; ++j) v[j] = nv[j];
}

__device__ __forceinline__ float remap_clamp(float x) {
  float xr = (x + 1.0f) * 0.5f * (float)(NPT - 1);
  return fminf(fmaxf(xr, 0.0f), (float)(NPT - 1));
}

// Round-6 configuration: the measured session optimum (79.2 us total, kernel ~38.6 us).
//  - single-phase: stage everything, ONE barrier, nothing held in regs across it
//    (the compiler always allocates 64 VGPRs for this kernel; any staged state live
//    across a contraction spills to scratch -- measured 4x: rounds 4/5/8/10).
//  - __launch_bounds__(1024,1): LDS (152 KB) caps occupancy at 1 block/CU anyway.
//  - x float4 load hoisted above staging (latency hidden under the staging stream).
//  - mid-core staging via float2 loads; b16 LDS writes (write conflicts measured
//    negligible: r0's 3.9M total ~= r4/5's write-conflict-free 4.2M).
__global__ __launch_bounds__(1024, 1) void tt_kernel(
    const float* __restrict__ x,  const float* __restrict__ g0,
    const float* __restrict__ g1, const float* __restrict__ g2,
    const float* __restrict__ g3, float* __restrict__ out, int npts)
{
  extern __shared__ char smem[];
  unsigned short* c1 = (unsigned short*)smem;          // [128][264] bf16
  unsigned short* c2 = c1 + NPT * MIDROW;              // [128][264] bf16
  float* c0 = (float*)(c2 + NPT * MIDROW);             // [128][20] fp32
  float* c3 = c0 + NPT * EDGEROW;                      // [128][20] fp32

  const int tid = (int)threadIdx.x;
  const int p0i = (int)blockIdx.x * (int)blockDim.x + tid;
  const int pc  = min(p0i, npts - 1);

  // hoisted: x load retires under the staging stream
  float4 xv = reinterpret_cast<const float4*>(x)[pc];

  // Stage mid cores: global [i][n][j] fp32 -> LDS [n][j*16+i] bf16 (RNE).
  // float2 per core per iter (e even -> j, j+1 share i, n). 16 iters.
  for (int t = tid; t < (RNK * NPT * RNK) / 2; t += 1024) {
    int e = 2 * t;
    int i = e >> 11;
    int n = (e >> 4) & (NPT - 1);
    int j = e & 15;
    float2 a = *(const float2*)(g1 + e);
    float2 b = *(const float2*)(g2 + e);
    __hip_bfloat16 h;
    h = __float2bfloat16(a.x); c1[n * MIDROW + j * 16 + i]       = *(u16*)&h;
    h = __float2bfloat16(a.y); c1[n * MIDROW + (j + 1) * 16 + i] = *(u16*)&h;
    h = __float2bfloat16(b.x); c2[n * MIDROW + j * 16 + i]       = *(u16*)&h;
    h = __float2bfloat16(b.y); c2[n * MIDROW + (j + 1) * 16 + i] = *(u16*)&h;
  }
  // Stage edge cores (fp32): core0 [1][n][j] -> [n][j]; core3 [i][n][1] -> [n][i]
  for (int t = tid; t < NPT * RNK; t += 1024) {
    int n = t >> 4;
    int i = t & (RNK - 1);
    c0[n * EDGEROW + i] = g0[t];               // flat n*16+j == t
    c3[n * EDGEROW + i] = g3[i * NPT + n];
  }
  __syncthreads();

  if (p0i >= npts) return;

  float v[16];
  // dim 0: v = lerp of core0 rows
  {
    float xc = remap_clamp(xv.x);
    int n0 = (int)xc; float w = xc - (float)n0; int n1 = min(n0 + 1, NPT - 1);
    const float4* L = (const float4*)(c0 + n0 * EDGEROW);
    const float4* H = (const float4*)(c0 + n1 * EDGEROW);
#pragma unroll
    for (int k = 0; k < 4; ++k) {
      float4 l = L[k], h = H[k];
      v[4*k+0] = fmaf(w, h.x - l.x, l.x);
      v[4*k+1] = fmaf(w, h.y - l.y, l.y);
      v[4*k+2] = fmaf(w, h.z - l.z, l.z);
      v[4*k+3] = fmaf(w, h.w - l.w, l.w);
    }
  }
  // dims 1, 2
  tt_mid((const uint32*)c1, remap_clamp(xv.y), v);
  tt_mid((const uint32*)c2, remap_clamp(xv.z), v);
  // dim 3: dot with lerped core3 column
  float acc;
  {
    float xc = remap_clamp(xv.w);
    int n0 = (int)xc; float w = xc - (float)n0; int n1 = min(n0 + 1, NPT - 1);
    const float4* L = (const float4*)(c3 + n0 * EDGEROW);
    const float4* H = (const float4*)(c3 + n1 * EDGEROW);
    float a0 = 0.f, a1 = 0.f, a2 = 0.f, a3 = 0.f;
#pragma unroll
    for (int k = 0; k < 4; ++k) {
      float4 l = L[k], h = H[k];
      a0 = fmaf(v[4*k+0], fmaf(w, h.x - l.x, l.x), a0);
      a1 = fmaf(v[4*k+1], fmaf(w, h.y - l.y, l.y), a1);
      a2 = fmaf(v[4*k+2], fmaf(w, h.z - l.z, l.z), a2);
      a3 = fmaf(v[4*k+3], fmaf(w, h.w - l.w, l.w), a3);
    }
    acc = (a0 + a1) + (a2 + a3);
  }
  out[p0i] = acc;
}

extern "C" void kernel_launch(void* const* d_in, const int* in_sizes, int n_in,
                              void* d_out, int out_size, void* d_ws, size_t ws_size,
                              hipStream_t stream) {
  const float* x  = (const float*)d_in[0];
  const float* g0 = (const float*)d_in[1];
  const float* g1 = (const float*)d_in[2];
  const float* g2 = (const float*)d_in[3];
  const float* g3 = (const float*)d_in[4];
  float* out = (float*)d_out;

  int B = in_sizes[0] / 4;
  // >64 KB dynamic LDS needs the opt-in attribute (host-side call, capture-safe)
  hipFuncSetAttribute(reinterpret_cast<const void*>(tt_kernel),
                      hipFuncAttributeMaxDynamicSharedMemorySize, SMEM_BYTES);
  int block = 1024;
  int grid = (B + block - 1) / block;   // 256 blocks -> 1 per CU
  tt_kernel<<<grid, block, SMEM_BYTES, stream>>>(x, g0, g1, g2, g3, out, B);
}